// Round 12
// baseline (104.447 us; speedup 1.0000x reference)
//
#include <hip/hip_runtime.h>
#include <math.h>

// FeedForwardQuantum collapsed closed-form (verified rounds 1-11):
//   q_j  = dot(x[n], W1[j]) + b1[j]                      (j = 0..7 only)
//   zp_j = R_j * cos(q_j + d_j),  R_j,d_j from (phi_j, theta_j, b1_j)
//   qout[i] = prod_{j<=i} zp_j (i>=1);  qout[0] = prod_{j=1..7} zp_j
//   out[n][k] = b2[k] + sum_j qout[j] * W2[k][j]
//
// Round-12 = round-11 (best: dur_us 100.6) with ONE change: non-temporal
// stores -> normal stores. Row-sequential full-4KB-row store order is kept
// (the verified 0.98x write-amplification shape); normal stores let the
// 33.5 MB output retire into L2 (32 MB aggregate, ~34.5 TB/s) instead of
// draining to HBM inside the kernel's lifetime.
//   - 512 blocks x 256 thr, 16 rows/block (4/wave); W1 + W2^T staged in
//     64 KB LDS once per block; single barrier.

constexpr int EMBED = 1024;
constexpr int NQ    = 8;
constexpr int BLOCK = 256;           // 4 waves
constexpr int RPW   = 4;             // rows per wave
constexpr int BR    = 16;            // rows per block
constexpr float INV2PI = 0.15915494309189535f;

__global__ __launch_bounds__(BLOCK, 2)
void ffq(const float* __restrict__ x,    // [rows][1024]
         const float* __restrict__ W1,   // [4096][1024] rows 0..7 used
         const float* __restrict__ b1,   // [4096]
         const float* __restrict__ qp,   // [8][3]
         const float* __restrict__ W2,   // [1024][8]
         const float* __restrict__ b2,   // [1024]
         float* __restrict__ out,        // [rows][1024]
         int total_rows)
{
    const int t    = threadIdx.x;
    const int lane = t & 63;
    const int wv   = t >> 6;
    const int j    = lane & 7;

    __shared__ float w1s[NQ * EMBED];    // 32 KB, [j][1024]
    __shared__ float w2t[NQ * EMBED];    // 32 KB, W2 transposed: [j][1024]

    const long r0 = (long)blockIdx.x * BR + wv * RPW;

    // ---- issue x loads FIRST (latency hides under LDS staging) ----
    float4 xv[RPW][4];
#pragma unroll
    for (int r = 0; r < RPW; ++r) {
        long row = r0 + r; if (row >= total_rows) row = total_rows - 1;
#pragma unroll
        for (int i = 0; i < 4; ++i)
            xv[r][i] = *reinterpret_cast<const float4*>(
                x + (size_t)row * EMBED + i * 256 + lane * 4);
    }

    // ---- stage W1 (straight copy) and W2^T into LDS ----
    {
        const float4* w1g = reinterpret_cast<const float4*>(W1);
        float4* w1d = reinterpret_cast<float4*>(w1s);
#pragma unroll
        for (int k = 0; k < (NQ * EMBED / 4) / BLOCK; ++k)   // 8 iters
            w1d[k * BLOCK + t] = w1g[k * BLOCK + t];
#pragma unroll
        for (int m = 0; m < 4; ++m) {
            const int col = m * BLOCK + t;
            const float4 a = *reinterpret_cast<const float4*>(W2 + col * NQ);
            const float4 b = *reinterpret_cast<const float4*>(W2 + col * NQ + 4);
            w2t[0 * EMBED + col] = a.x;  w2t[1 * EMBED + col] = a.y;
            w2t[2 * EMBED + col] = a.z;  w2t[3 * EMBED + col] = a.w;
            w2t[4 * EMBED + col] = b.x;  w2t[5 * EMBED + col] = b.y;
            w2t[6 * EMBED + col] = b.z;  w2t[7 * EMBED + col] = b.w;
        }
    }

    // ---- per-lane qubit constants (qubit j = lane&7) ----
    float Rj, qoffj;
    {
        const float phi  = qp[j * 3 + 0];
        const float th   = qp[j * 3 + 1];
        const float cth  = cosf(th);
        const float ssps = sinf(th) * sinf(phi);
        Rj    = sqrtf(cth * cth + ssps * ssps);
        qoffj = (b1[j] + atan2f(ssps, cth)) * INV2PI;     // revolutions
    }

    // ---- b2 fragment (coalesced) ----
    float4 b2v[4];
#pragma unroll
    for (int i = 0; i < 4; ++i)
        b2v[i] = *reinterpret_cast<const float4*>(b2 + i * 256 + lane * 4);

    __syncthreads();     // staging complete (only barrier)

    // ---- phase 1: dots. W1 fragment read ONCE, reused across 4 rows ----
    float p[RPW][NQ];
#pragma unroll
    for (int r = 0; r < RPW; ++r)
#pragma unroll
        for (int jj = 0; jj < NQ; ++jj) p[r][jj] = 0.f;

#pragma unroll
    for (int i = 0; i < 4; ++i) {
#pragma unroll
        for (int jj = 0; jj < NQ; ++jj) {
            const float4 w = *reinterpret_cast<const float4*>(
                w1s + jj * EMBED + i * 256 + lane * 4);
#pragma unroll
            for (int r = 0; r < RPW; ++r) {
                p[r][jj] = fmaf(xv[r][i].x, w.x, p[r][jj]);
                p[r][jj] = fmaf(xv[r][i].y, w.y, p[r][jj]);
                p[r][jj] = fmaf(xv[r][i].z, w.z, p[r][jj]);
                p[r][jj] = fmaf(xv[r][i].w, w.w, p[r][jj]);
            }
        }
    }

    // ---- per-row: reduce -> trig -> gather -> prefix (round-2 verified) ----
    float qo[RPW][NQ];
#pragma unroll
    for (int r = 0; r < RPW; ++r) {
        float q4[4], q2[2], tsum;
        {
            const bool up = (lane & 4);
#pragma unroll
            for (int k = 0; k < 4; ++k) {
                const float snd = up ? p[r][k]     : p[r][k + 4];
                const float kp  = up ? p[r][k + 4] : p[r][k];
                q4[k] = kp + __shfl_xor(snd, 4, 64);
            }
        }
        {
            const bool up = (lane & 2);
#pragma unroll
            for (int k = 0; k < 2; ++k) {
                const float snd = up ? q4[k]     : q4[k + 2];
                const float kp  = up ? q4[k + 2] : q4[k];
                q2[k] = kp + __shfl_xor(snd, 2, 64);
            }
        }
        {
            const bool up = (lane & 1);
            const float snd = up ? q2[0] : q2[1];
            const float kp  = up ? q2[1] : q2[0];
            tsum = kp + __shfl_xor(snd, 1, 64);
        }
        tsum += __shfl_xor(tsum, 8, 64);
        tsum += __shfl_xor(tsum, 16, 64);
        tsum += __shfl_xor(tsum, 32, 64);

        const float zz = Rj * __builtin_amdgcn_cosf(tsum * INV2PI + qoffj);

        // ordered all-gather of zp[0..7] (masks 1,2,4)
        float z0_, z1_, z2_, z3_, z4_, z5_, z6_, z7_;
        {
            const float o  = __shfl_xor(zz, 1, 64);
            const float a0 = (lane & 1) ? o  : zz;
            const float a1 = (lane & 1) ? zz : o;
            const float rA = __shfl_xor(a0, 2, 64);
            const float rB = __shfl_xor(a1, 2, 64);
            const float c0 = (lane & 2) ? rA : a0;
            const float c1 = (lane & 2) ? rB : a1;
            const float c2 = (lane & 2) ? a0 : rA;
            const float c3 = (lane & 2) ? a1 : rB;
            const float d0 = __shfl_xor(c0, 4, 64);
            const float d1 = __shfl_xor(c1, 4, 64);
            const float d2 = __shfl_xor(c2, 4, 64);
            const float d3 = __shfl_xor(c3, 4, 64);
            z0_ = (lane & 4) ? d0 : c0;
            z1_ = (lane & 4) ? d1 : c1;
            z2_ = (lane & 4) ? d2 : c2;
            z3_ = (lane & 4) ? d3 : c3;
            z4_ = (lane & 4) ? c0 : d0;
            z5_ = (lane & 4) ? c1 : d1;
            z6_ = (lane & 4) ? c2 : d2;
            z7_ = (lane & 4) ? c3 : d3;
        }

        qo[r][1] = z0_ * z1_;
        qo[r][2] = qo[r][1] * z2_;
        qo[r][3] = qo[r][2] * z3_;
        qo[r][4] = qo[r][3] * z4_;
        qo[r][5] = qo[r][4] * z5_;
        qo[r][6] = qo[r][5] * z6_;
        qo[r][7] = qo[r][6] * z7_;
        qo[r][0] = z1_ * z2_ * z3_ * z4_ * z5_ * z6_ * z7_;
    }

    // ---- phase 2: ROW-OUTER, chunk-inner. Each 4 KB row written fully,
    //      sequentially; W2T frags re-read from LDS per row (cheap);
    //      NORMAL stores (L2 write-back absorbs the 33.5 MB output) ----
#pragma unroll
    for (int r = 0; r < RPW; ++r) {
        const long row = r0 + r;
        if (row >= total_rows) break;         // wave-uniform

        float* outp = out + (size_t)row * EMBED;

#pragma unroll
        for (int i = 0; i < 4; ++i) {
            float4 w[NQ];
#pragma unroll
            for (int jj = 0; jj < NQ; ++jj)
                w[jj] = *reinterpret_cast<const float4*>(
                    w2t + jj * EMBED + i * 256 + lane * 4);

            float4 o = b2v[i];
#pragma unroll
            for (int jj = 0; jj < NQ; ++jj) {
                o.x = fmaf(qo[r][jj], w[jj].x, o.x);
                o.y = fmaf(qo[r][jj], w[jj].y, o.y);
                o.z = fmaf(qo[r][jj], w[jj].z, o.z);
                o.w = fmaf(qo[r][jj], w[jj].w, o.w);
            }

            *reinterpret_cast<float4*>(outp + i * 256 + lane * 4) = o;
        }
    }
}

extern "C" void kernel_launch(void* const* d_in, const int* in_sizes, int n_in,
                              void* d_out, int out_size, void* d_ws, size_t ws_size,
                              hipStream_t stream) {
    const float* x  = (const float*)d_in[0];
    const float* W1 = (const float*)d_in[1];
    const float* b1 = (const float*)d_in[2];
    const float* qp = (const float*)d_in[3];
    const float* W2 = (const float*)d_in[4];
    const float* b2 = (const float*)d_in[5];
    float* out = (float*)d_out;

    const int rows = in_sizes[0] / EMBED;          // 8192
    const int grid = (rows + BR - 1) / BR;         // 512

    hipLaunchKernelGGL(ffq, dim3(grid), dim3(BLOCK), 0, stream,
                       x, W1, b1, qp, W2, b2, out, rows);
}

// Round 13
// 100.407 us; speedup vs baseline: 1.0402x; 1.0402x over previous
//
#include <hip/hip_runtime.h>
#include <math.h>

// FeedForwardQuantum collapsed closed-form (verified rounds 1-12):
//   q_j  = dot(x[n], W1[j]) + b1[j]                      (j = 0..7 only)
//   zp_j = R_j * cos(q_j + d_j),  R_j,d_j from (phi_j, theta_j, b1_j)
//   qout[i] = prod_{j<=i} zp_j (i>=1);  qout[0] = prod_{j=1..7} zp_j
//   out[n][k] = b2[k] + sum_j qout[j] * W2[k][j]
//
// Round-13 = round-11 (best: 100.6) with phase-2 LDS hoist:
//   - chunk-outer COMPUTE: W2T frag (8 float4) read once per chunk from LDS,
//     reused across the wave's 4 rows -> 32 ds_read_b128/lane (was 128).
//     Results accumulate in a register tile oreg[4][4] (all indices static).
//   - store-only pass afterwards: row-sequential full-4KB rows, NT stores
//     (the measured 0.98x write-amplification shape, kept from round 11).
//   - 512 blocks x 256 thr, 16 rows/block; W1+W2T in 64 KB LDS; 1 barrier.

constexpr int EMBED = 1024;
constexpr int NQ    = 8;
constexpr int BLOCK = 256;           // 4 waves
constexpr int RPW   = 4;             // rows per wave
constexpr int BR    = 16;            // rows per block
constexpr float INV2PI = 0.15915494309189535f;

using v4f = __attribute__((ext_vector_type(4))) float;

__global__ __launch_bounds__(BLOCK, 2)
void ffq(const float* __restrict__ x,    // [rows][1024]
         const float* __restrict__ W1,   // [4096][1024] rows 0..7 used
         const float* __restrict__ b1,   // [4096]
         const float* __restrict__ qp,   // [8][3]
         const float* __restrict__ W2,   // [1024][8]
         const float* __restrict__ b2,   // [1024]
         float* __restrict__ out,        // [rows][1024]
         int total_rows)
{
    const int t    = threadIdx.x;
    const int lane = t & 63;
    const int wv   = t >> 6;
    const int j    = lane & 7;

    __shared__ float w1s[NQ * EMBED];    // 32 KB, [j][1024]
    __shared__ float w2t[NQ * EMBED];    // 32 KB, W2 transposed: [j][1024]

    const long r0 = (long)blockIdx.x * BR + wv * RPW;

    // ---- issue x loads FIRST (latency hides under LDS staging) ----
    float4 xv[RPW][4];
#pragma unroll
    for (int r = 0; r < RPW; ++r) {
        long row = r0 + r; if (row >= total_rows) row = total_rows - 1;
#pragma unroll
        for (int i = 0; i < 4; ++i)
            xv[r][i] = *reinterpret_cast<const float4*>(
                x + (size_t)row * EMBED + i * 256 + lane * 4);
    }

    // ---- stage W1 (straight copy) and W2^T into LDS ----
    {
        const float4* w1g = reinterpret_cast<const float4*>(W1);
        float4* w1d = reinterpret_cast<float4*>(w1s);
#pragma unroll
        for (int k = 0; k < (NQ * EMBED / 4) / BLOCK; ++k)   // 8 iters
            w1d[k * BLOCK + t] = w1g[k * BLOCK + t];
#pragma unroll
        for (int m = 0; m < 4; ++m) {
            const int col = m * BLOCK + t;
            const float4 a = *reinterpret_cast<const float4*>(W2 + col * NQ);
            const float4 b = *reinterpret_cast<const float4*>(W2 + col * NQ + 4);
            w2t[0 * EMBED + col] = a.x;  w2t[1 * EMBED + col] = a.y;
            w2t[2 * EMBED + col] = a.z;  w2t[3 * EMBED + col] = a.w;
            w2t[4 * EMBED + col] = b.x;  w2t[5 * EMBED + col] = b.y;
            w2t[6 * EMBED + col] = b.z;  w2t[7 * EMBED + col] = b.w;
        }
    }

    // ---- per-lane qubit constants (qubit j = lane&7) ----
    float Rj, qoffj;
    {
        const float phi  = qp[j * 3 + 0];
        const float th   = qp[j * 3 + 1];
        const float cth  = cosf(th);
        const float ssps = sinf(th) * sinf(phi);
        Rj    = sqrtf(cth * cth + ssps * ssps);
        qoffj = (b1[j] + atan2f(ssps, cth)) * INV2PI;     // revolutions
    }

    // ---- b2 fragment (coalesced) ----
    float4 b2v[4];
#pragma unroll
    for (int i = 0; i < 4; ++i)
        b2v[i] = *reinterpret_cast<const float4*>(b2 + i * 256 + lane * 4);

    __syncthreads();     // staging complete (only barrier)

    // ---- phase 1: dots. W1 fragment read ONCE, reused across 4 rows ----
    float p[RPW][NQ];
#pragma unroll
    for (int r = 0; r < RPW; ++r)
#pragma unroll
        for (int jj = 0; jj < NQ; ++jj) p[r][jj] = 0.f;

#pragma unroll
    for (int i = 0; i < 4; ++i) {
#pragma unroll
        for (int jj = 0; jj < NQ; ++jj) {
            const float4 w = *reinterpret_cast<const float4*>(
                w1s + jj * EMBED + i * 256 + lane * 4);
#pragma unroll
            for (int r = 0; r < RPW; ++r) {
                p[r][jj] = fmaf(xv[r][i].x, w.x, p[r][jj]);
                p[r][jj] = fmaf(xv[r][i].y, w.y, p[r][jj]);
                p[r][jj] = fmaf(xv[r][i].z, w.z, p[r][jj]);
                p[r][jj] = fmaf(xv[r][i].w, w.w, p[r][jj]);
            }
        }
    }

    // ---- per-row: reduce -> trig -> gather -> prefix (round-2 verified) ----
    float qo[RPW][NQ];
#pragma unroll
    for (int r = 0; r < RPW; ++r) {
        float q4[4], q2[2], tsum;
        {
            const bool up = (lane & 4);
#pragma unroll
            for (int k = 0; k < 4; ++k) {
                const float snd = up ? p[r][k]     : p[r][k + 4];
                const float kp  = up ? p[r][k + 4] : p[r][k];
                q4[k] = kp + __shfl_xor(snd, 4, 64);
            }
        }
        {
            const bool up = (lane & 2);
#pragma unroll
            for (int k = 0; k < 2; ++k) {
                const float snd = up ? q4[k]     : q4[k + 2];
                const float kp  = up ? q4[k + 2] : q4[k];
                q2[k] = kp + __shfl_xor(snd, 2, 64);
            }
        }
        {
            const bool up = (lane & 1);
            const float snd = up ? q2[0] : q2[1];
            const float kp  = up ? q2[1] : q2[0];
            tsum = kp + __shfl_xor(snd, 1, 64);
        }
        tsum += __shfl_xor(tsum, 8, 64);
        tsum += __shfl_xor(tsum, 16, 64);
        tsum += __shfl_xor(tsum, 32, 64);

        const float zz = Rj * __builtin_amdgcn_cosf(tsum * INV2PI + qoffj);

        // ordered all-gather of zp[0..7] (masks 1,2,4)
        float z0_, z1_, z2_, z3_, z4_, z5_, z6_, z7_;
        {
            const float o  = __shfl_xor(zz, 1, 64);
            const float a0 = (lane & 1) ? o  : zz;
            const float a1 = (lane & 1) ? zz : o;
            const float rA = __shfl_xor(a0, 2, 64);
            const float rB = __shfl_xor(a1, 2, 64);
            const float c0 = (lane & 2) ? rA : a0;
            const float c1 = (lane & 2) ? rB : a1;
            const float c2 = (lane & 2) ? a0 : rA;
            const float c3 = (lane & 2) ? a1 : rB;
            const float d0 = __shfl_xor(c0, 4, 64);
            const float d1 = __shfl_xor(c1, 4, 64);
            const float d2 = __shfl_xor(c2, 4, 64);
            const float d3 = __shfl_xor(c3, 4, 64);
            z0_ = (lane & 4) ? d0 : c0;
            z1_ = (lane & 4) ? d1 : c1;
            z2_ = (lane & 4) ? d2 : c2;
            z3_ = (lane & 4) ? d3 : c3;
            z4_ = (lane & 4) ? c0 : d0;
            z5_ = (lane & 4) ? c1 : d1;
            z6_ = (lane & 4) ? c2 : d2;
            z7_ = (lane & 4) ? c3 : d3;
        }

        qo[r][1] = z0_ * z1_;
        qo[r][2] = qo[r][1] * z2_;
        qo[r][3] = qo[r][2] * z3_;
        qo[r][4] = qo[r][3] * z4_;
        qo[r][5] = qo[r][4] * z5_;
        qo[r][6] = qo[r][5] * z6_;
        qo[r][7] = qo[r][6] * z7_;
        qo[r][0] = z1_ * z2_ * z3_ * z4_ * z5_ * z6_ * z7_;
    }

    // ---- phase 2a: chunk-outer COMPUTE into register tile.
    //      W2T frag read ONCE per chunk (32 ds_read_b128/lane total),
    //      reused across 4 rows. All indices compile-time constant. ----
    float4 oreg[RPW][4];
#pragma unroll
    for (int r = 0; r < RPW; ++r)
#pragma unroll
        for (int i = 0; i < 4; ++i)
            oreg[r][i] = b2v[i];

#pragma unroll
    for (int i = 0; i < 4; ++i) {
        float4 w[NQ];
#pragma unroll
        for (int jj = 0; jj < NQ; ++jj)
            w[jj] = *reinterpret_cast<const float4*>(
                w2t + jj * EMBED + i * 256 + lane * 4);

#pragma unroll
        for (int r = 0; r < RPW; ++r) {
#pragma unroll
            for (int jj = 0; jj < NQ; ++jj) {
                oreg[r][i].x = fmaf(qo[r][jj], w[jj].x, oreg[r][i].x);
                oreg[r][i].y = fmaf(qo[r][jj], w[jj].y, oreg[r][i].y);
                oreg[r][i].z = fmaf(qo[r][jj], w[jj].z, oreg[r][i].z);
                oreg[r][i].w = fmaf(qo[r][jj], w[jj].w, oreg[r][i].w);
            }
        }
    }

    // ---- phase 2b: store-only pass, ROW-SEQUENTIAL full 4 KB rows,
    //      non-temporal (the measured 0.98x write shape) ----
#pragma unroll
    for (int r = 0; r < RPW; ++r) {
        const long row = r0 + r;
        if (row >= total_rows) break;         // wave-uniform

        float* outp = out + (size_t)row * EMBED;
#pragma unroll
        for (int i = 0; i < 4; ++i) {
            v4f ov = {oreg[r][i].x, oreg[r][i].y, oreg[r][i].z, oreg[r][i].w};
            __builtin_nontemporal_store(
                ov, reinterpret_cast<v4f*>(outp + i * 256 + lane * 4));
        }
    }
}

extern "C" void kernel_launch(void* const* d_in, const int* in_sizes, int n_in,
                              void* d_out, int out_size, void* d_ws, size_t ws_size,
                              hipStream_t stream) {
    const float* x  = (const float*)d_in[0];
    const float* W1 = (const float*)d_in[1];
    const float* b1 = (const float*)d_in[2];
    const float* qp = (const float*)d_in[3];
    const float* W2 = (const float*)d_in[4];
    const float* b2 = (const float*)d_in[5];
    float* out = (float*)d_out;

    const int rows = in_sizes[0] / EMBED;          // 8192
    const int grid = (rows + BR - 1) / BR;         // 512

    hipLaunchKernelGGL(ffq, dim3(grid), dim3(BLOCK), 0, stream,
                       x, W1, b1, qp, W2, b2, out, rows);
}